// Round 1
// baseline (1383.545 us; speedup 1.0000x reference)
//
#include <hip/hip_runtime.h>
#include <cstddef>
#include <cstdint>

#define NN 50000
#define DEG 8
#define EE (NN*DEG)
#define HD 128

// ---------------------------------------------------------------------------
// K0: build neighbor lists (CSR with constant degree 8) via atomic counters
// fwd_nbr[d*8+k] = src of k-th incoming edge of d (fwd relation)
// rev_nbr[s*8+k] = dst of k-th edge whose src is s (rev relation)
// ---------------------------------------------------------------------------
__global__ void k_build_nbr(const int* __restrict__ ef, int* __restrict__ cnt,
                            int* __restrict__ fwd_nbr, int* __restrict__ rev_nbr) {
    int e = blockIdx.x * blockDim.x + threadIdx.x;
    if (e >= EE) return;
    int s = ef[e], d = ef[EE + e];
    int p = atomicAdd(&cnt[d], 1);
    fwd_nbr[d * DEG + p] = s;
    int q = atomicAdd(&cnt[NN + s], 1);
    rev_nbr[s * DEG + q] = d;
}

// ---------------------------------------------------------------------------
// K0b: fold post_W [16][416][32] -> Pfold [16][160][32]
// (deg==8 everywhere -> both degree scalers are exactly 1, so the three 4F agg
//  blocks collapse: rows 32:160 = sum of post rows 32:160,160:288,288:416)
// ---------------------------------------------------------------------------
__global__ void k_fold_post(const float* __restrict__ post_W, float* __restrict__ Pfold) {
    int idx = blockIdx.x * blockDim.x + threadIdx.x;
    const int total = 16 * 160 * 32;
    if (idx >= total) return;
    int g = idx & 31;
    int row = (idx >> 5) % 160;
    int m = idx / (160 * 32);
    const float* W = post_W + (size_t)m * 416 * 32;
    float v;
    if (row < 32) v = W[row * 32 + g];
    else {
        int r = row - 32;
        v = W[(32 + r) * 32 + g] + W[(160 + r) * 32 + g] + W[(288 + r) * 32 + g];
    }
    Pfold[idx] = v;
}

// ---------------------------------------------------------------------------
// K1/K4/K7a: generic [nrows,128] @ [128,128] + bias, optional relu/accumulate/
// BN partial sums. W staged in two 64-row chunks (32KB), X tile 32 rows (16KB).
// ---------------------------------------------------------------------------
template<int RELU, int ACCUM, int BN>
__global__ __launch_bounds__(256) void k_gemm128(
    const float* __restrict__ X, const float* __restrict__ W,
    const float* __restrict__ b, float* __restrict__ Y, int nrows,
    float* __restrict__ bnsum, float* __restrict__ bnsum2) {
    __shared__ float Ws[64 * 128];
    __shared__ float Xs[32 * 128];
    int tid = threadIdx.x;
    int row0 = blockIdx.x * 32;
    for (int i = tid; i < 32 * 128; i += 256) {
        int r = row0 + (i >> 7);
        Xs[i] = (r < nrows) ? X[(size_t)r * 128 + (i & 127)] : 0.f;
    }
    int col = tid & 127, rb = tid >> 7;
    float acc[16];
#pragma unroll
    for (int i = 0; i < 16; i++) acc[i] = 0.f;
    for (int kc = 0; kc < 2; kc++) {
        __syncthreads();
        for (int i = tid; i < 64 * 128; i += 256) Ws[i] = W[kc * 64 * 128 + i];
        __syncthreads();
        for (int k = 0; k < 64; k++) {
            float w = Ws[k * 128 + col];
#pragma unroll
            for (int i = 0; i < 16; i++)
                acc[i] += Xs[(rb + 2 * i) * 128 + kc * 64 + k] * w;
        }
    }
    float bias = b[col];
    float ls = 0.f, ls2 = 0.f;
#pragma unroll
    for (int i = 0; i < 16; i++) {
        int r = row0 + rb + 2 * i;
        if (r < nrows) {
            float v = acc[i] + bias;
            if (ACCUM) v += Y[(size_t)r * 128 + col];
            if (RELU) v = fmaxf(v, 0.f);
            Y[(size_t)r * 128 + col] = v;
            if (BN) { ls += v; ls2 += v * v; }
        }
    }
    if (BN) {
        __syncthreads();
        Xs[tid] = ls; Xs[256 + tid] = ls2;
        __syncthreads();
        if (tid < 128) {
            atomicAdd(&bnsum[col], Xs[tid] + Xs[tid + 128]);
            atomicAdd(&bnsum2[col], Xs[256 + tid] + Xs[256 + tid + 128]);
        }
    }
}

// ---------------------------------------------------------------------------
// K2: B planes. B_r[n,c] = h[n, t*32..] @ pre_W[l,r,t, 32+f, g]  (src-side half)
// Bplanes layout: [2][N][128]
// ---------------------------------------------------------------------------
__global__ __launch_bounds__(256) void k_preB(
    const float* __restrict__ hbuf, const float* __restrict__ pre_W,
    int layer, float* __restrict__ Bplanes) {
    __shared__ float Wb[2 * 4 * 32 * 32];  // 32 KB: bottom halves, both relations
    __shared__ float Xs[16 * 128];         // 8 KB
    int tid = threadIdx.x;
    for (int i = tid; i < 8192; i += 256) {
        int g = i & 31, f = (i >> 5) & 31, t = (i >> 10) & 3, r = i >> 12;
        Wb[i] = pre_W[((((layer * 2 + r) * 4 + t) * 64) + 32 + f) * 32 + g];
    }
    int r = tid >> 7, c = tid & 127, t = c >> 5, g = c & 31;
    const float* wp = &Wb[((r * 4 + t) * 32) * 32 + g];
    for (int base = blockIdx.x * 16; base < NN; base += gridDim.x * 16) {
        __syncthreads();
        for (int i = tid; i < 16 * 128; i += 256) {
            int n = base + (i >> 7);
            Xs[i] = (n < NN) ? hbuf[(size_t)n * 128 + (i & 127)] : 0.f;
        }
        __syncthreads();
        for (int n = 0; n < 16; n++) {
            if (base + n >= NN) break;
            float acc = 0.f;
#pragma unroll
            for (int f = 0; f < 32; f++) acc += Xs[n * 128 + t * 32 + f] * wp[f * 32];
            Bplanes[(size_t)r * NN * 128 + (size_t)(base + n) * 128 + c] = acc;
        }
    }
}

// ---------------------------------------------------------------------------
// K3: aggregation + folded post-GEMM for one (layer, relation), tower-pair
// split across blockIdx.y. msg_k = A[d] + B[nbr_k] + pre_b; A const across k:
//   mean = A+pre_b+mean(B), min = A+pre_b+min(B), max likewise,
//   std  = sqrt(relu(mean(B^2)-mean(B)^2)+1e-5)  (shift-invariant)
// ---------------------------------------------------------------------------
__global__ __launch_bounds__(256) void k_agg(
    const float* __restrict__ hbuf, const float* __restrict__ Bplane,
    const int* __restrict__ nbr, const float* __restrict__ pre_W,
    const float* __restrict__ pre_b, const float* __restrict__ post_b,
    const float* __restrict__ Pfold, int m, float* __restrict__ po) {
    __shared__ float Pf[2 * 160 * 32];  // 40 KB: folded post, 2 towers
    __shared__ float Wt[2 * 32 * 32];   // 8 KB: pre_W top (dst-side), 2 towers
    __shared__ float stats[4][5 * 64];  // 5 KB: [xt|mean|mn|mx|std] x 4 nodes
    int tid = threadIdx.x;
    int ty = blockIdx.y;  // tower pair: towers 2ty, 2ty+1
    for (int i = tid; i < 2 * 160 * 32; i += 256) {
        int tl = i / (160 * 32);
        Pf[i] = Pfold[(size_t)m * 4 * 160 * 32 + (2 * ty + tl) * 160 * 32 + (i - tl * 160 * 32)];
    }
    for (int i = tid; i < 2 * 32 * 32; i += 256) {
        int tl = i >> 10, f = (i >> 5) & 31, g = i & 31;
        Wt[i] = pre_W[((m * 4 + 2 * ty + tl) * 64 + f) * 32 + g];
    }
    __syncthreads();
    int slot = tid >> 6;        // node slot 0..3
    int cl = tid & 63;          // local feature
    int tl = cl >> 5, g = cl & 31;
    int c = (2 * ty + tl) * 32 + g;  // global feature
    float preb = pre_b[m * 128 + c];
    float postb = post_b[m * 128 + c];
    for (int base = blockIdx.x * 4; base < NN; base += gridDim.x * 4) {
        int d = base + slot;
        bool valid = d < NN;
        float xc = valid ? hbuf[(size_t)d * 128 + c] : 0.f;
        stats[slot][cl] = xc;
        __syncthreads();
        float A = 0.f;
#pragma unroll
        for (int f = 0; f < 32; f++) A += stats[slot][tl * 32 + f] * Wt[(tl * 32 + f) * 32 + g];
        float s = 0.f, s2 = 0.f, mn = 1e30f, mx = -1e30f;
        if (valid) {
            const int* nb = &nbr[d * 8];
#pragma unroll
            for (int k = 0; k < 8; k++) {
                float bv = Bplane[(size_t)nb[k] * 128 + c];
                s += bv; s2 += bv * bv; mn = fminf(mn, bv); mx = fmaxf(mx, bv);
            }
        }
        float Bm = s * 0.125f;
        float stdv = sqrtf(fmaxf(s2 * 0.125f - Bm * Bm, 0.f) + 1e-5f);
        float bse = A + preb;
        stats[slot][64 + cl] = bse + Bm;
        stats[slot][128 + cl] = bse + mn;
        stats[slot][192 + cl] = bse + mx;
        stats[slot][256 + cl] = stdv;
        __syncthreads();
        float acc = postb;
        const float* P = &Pf[tl * 160 * 32 + g];
        const float* S = &stats[slot][tl * 32];
#pragma unroll
        for (int f = 0; f < 32; f++) {
            acc += S[f]        * P[f * 32];
            acc += S[64 + f]   * P[(32 + f) * 32];
            acc += S[128 + f]  * P[(64 + f) * 32];
            acc += S[192 + f]  * P[(96 + f) * 32];
            acc += S[256 + f]  * P[(128 + f) * 32];
        }
        if (valid) po[(size_t)d * 128 + c] = acc;
        __syncthreads();
    }
}

// ---------------------------------------------------------------------------
// K5: BN finalize (1 block, 128 threads)
// ---------------------------------------------------------------------------
__global__ void k_bn_final(const float* __restrict__ bnsum, const float* __restrict__ bnsum2,
                           const float* __restrict__ gamma, const float* __restrict__ beta,
                           int layer, float* __restrict__ scale, float* __restrict__ shift) {
    int c = threadIdx.x;
    float mu = bnsum[c] * (1.f / NN);
    float var = bnsum2[c] * (1.f / NN) - mu * mu;
    float sc = gamma[layer * 128 + c] * rsqrtf(var + 1e-5f);
    scale[c] = sc;
    shift[c] = beta[layer * 128 + c] - mu * sc;
}

// ---------------------------------------------------------------------------
// K6: apply BN + relu (vectorized float4)
// ---------------------------------------------------------------------------
__global__ void k_bn_apply(const float4* __restrict__ y, const float* __restrict__ scale,
                           const float* __restrict__ shift, float4* __restrict__ hout) {
    int i = blockIdx.x * blockDim.x + threadIdx.x;
    if (i >= NN * 32) return;
    int cb = (i & 31) * 4;
    float4 v = y[i];
    v.x = fmaxf(scale[cb + 0] * v.x + shift[cb + 0], 0.f);
    v.y = fmaxf(scale[cb + 1] * v.y + shift[cb + 1], 0.f);
    v.z = fmaxf(scale[cb + 2] * v.z + shift[cb + 2], 0.f);
    v.w = fmaxf(scale[cb + 3] * v.w + shift[cb + 3], 0.f);
    hout[i] = v;
}

// ---------------------------------------------------------------------------
// K7b: [nrows,128] @ [128,32] + bias -> out
// ---------------------------------------------------------------------------
__global__ __launch_bounds__(256) void k_gemm_out(
    const float* __restrict__ X, const float* __restrict__ W,
    const float* __restrict__ b, float* __restrict__ Y, int nrows) {
    __shared__ float Ws[128 * 32];
    __shared__ float Xs[32 * 128];
    int tid = threadIdx.x;
    for (int i = tid; i < 128 * 32; i += 256) Ws[i] = W[i];
    int row0 = blockIdx.x * 32;
    for (int i = tid; i < 32 * 128; i += 256) {
        int r = row0 + (i >> 7);
        Xs[i] = (r < nrows) ? X[(size_t)r * 128 + (i & 127)] : 0.f;
    }
    __syncthreads();
    int col = tid & 31, rb = tid >> 5;
    float acc[4];
    float bias = b[col];
#pragma unroll
    for (int i = 0; i < 4; i++) acc[i] = bias;
    for (int k = 0; k < 128; k++) {
        float w = Ws[k * 32 + col];
#pragma unroll
        for (int i = 0; i < 4; i++) acc[i] += Xs[(rb + 8 * i) * 128 + k] * w;
    }
#pragma unroll
    for (int i = 0; i < 4; i++) {
        int r = row0 + rb + 8 * i;
        if (r < nrows) Y[(size_t)r * 32 + col] = acc[i];
    }
}

// ---------------------------------------------------------------------------
extern "C" void kernel_launch(void* const* d_in, const int* in_sizes, int n_in,
                              void* d_out, int out_size, void* d_ws, size_t ws_size,
                              hipStream_t stream) {
    const float* x      = (const float*)d_in[0];
    const float* W_in   = (const float*)d_in[1];
    const float* b_in   = (const float*)d_in[2];
    const float* pre_W  = (const float*)d_in[3];
    const float* pre_b  = (const float*)d_in[4];
    const float* post_W = (const float*)d_in[5];
    const float* post_b = (const float*)d_in[6];
    const float* lin_W  = (const float*)d_in[7];
    const float* lin_b  = (const float*)d_in[8];
    const float* bn_g   = (const float*)d_in[9];
    const float* bn_b   = (const float*)d_in[10];
    const float* mlp_W1 = (const float*)d_in[11];
    const float* mlp_b1 = (const float*)d_in[12];
    const float* mlp_W2 = (const float*)d_in[13];
    const float* mlp_b2 = (const float*)d_in[14];
    const int*   edge   = (const int*)d_in[15];
    float* out = (float*)d_out;

    // workspace layout
    char* w = (char*)d_ws;
    const size_t plane = (size_t)NN * 128 * sizeof(float);  // 25.6 MB
    float* hbuf = (float*)w; w += plane;
    float* ybuf = (float*)w; w += plane;
    float* Bpl  = (float*)w; w += 2 * plane;   // B0 | B1
    float* po0  = (float*)w; w += plane;
    float* po1  = (float*)w; w += plane;
    int* fwd_nbr = (int*)w; w += (size_t)NN * DEG * sizeof(int);
    int* rev_nbr = (int*)w; w += (size_t)NN * DEG * sizeof(int);
    int* cnt     = (int*)w; w += (size_t)2 * NN * sizeof(int);
    float* Pfold = (float*)w; w += (size_t)16 * 160 * 32 * sizeof(float);
    float* bnsum  = (float*)w; w += 128 * sizeof(float);
    float* bnsum2 = (float*)w; w += 128 * sizeof(float);
    float* scale  = (float*)w; w += 128 * sizeof(float);
    float* shift  = (float*)w; w += 128 * sizeof(float);

    const int gRows = (NN + 31) / 32;  // 1563

    hipMemsetAsync(cnt, 0, (size_t)2 * NN * sizeof(int), stream);
    k_build_nbr<<<(EE + 255) / 256, 256, 0, stream>>>(edge, cnt, fwd_nbr, rev_nbr);
    k_fold_post<<<(16 * 160 * 32 + 255) / 256, 256, 0, stream>>>(post_W, Pfold);

    // h = relu(x @ W_in + b_in)
    k_gemm128<1, 0, 0><<<gRows, 256, 0, stream>>>(x, W_in, b_in, hbuf, NN, nullptr, nullptr);

    for (int l = 0; l < 2; l++) {
        k_preB<<<256, 256, 0, stream>>>(hbuf, pre_W, l, Bpl);
        dim3 gag(256, 2);
        k_agg<<<gag, 256, 0, stream>>>(hbuf, Bpl, fwd_nbr, pre_W, pre_b, post_b,
                                       Pfold, l * 2 + 0, po0);
        k_agg<<<gag, 256, 0, stream>>>(hbuf, Bpl + (size_t)NN * 128, rev_nbr, pre_W, pre_b,
                                       post_b, Pfold, l * 2 + 1, po1);
        hipMemsetAsync(bnsum, 0, 2 * 128 * sizeof(float), stream);  // bnsum+bnsum2
        k_gemm128<0, 0, 0><<<gRows, 256, 0, stream>>>(
            po0, lin_W + (size_t)(l * 2 + 0) * 128 * 128, lin_b + (l * 2 + 0) * 128,
            ybuf, NN, nullptr, nullptr);
        k_gemm128<0, 1, 1><<<gRows, 256, 0, stream>>>(
            po1, lin_W + (size_t)(l * 2 + 1) * 128 * 128, lin_b + (l * 2 + 1) * 128,
            ybuf, NN, bnsum, bnsum2);
        k_bn_final<<<1, 128, 0, stream>>>(bnsum, bnsum2, bn_g, bn_b, l, scale, shift);
        k_bn_apply<<<(NN * 32 + 255) / 256, 256, 0, stream>>>(
            (const float4*)ybuf, scale, shift, (float4*)hbuf);
    }

    // out = relu(h @ mlp_W1 + b1) @ mlp_W2 + b2   (reuse po0 as tmp)
    k_gemm128<1, 0, 0><<<gRows, 256, 0, stream>>>(hbuf, mlp_W1, mlp_b1, po0, NN, nullptr, nullptr);
    k_gemm_out<<<gRows, 256, 0, stream>>>(po0, mlp_W2, mlp_b2, out, NN);
}

// Round 2
// 1135.183 us; speedup vs baseline: 1.2188x; 1.2188x over previous
//
#include <hip/hip_runtime.h>
#include <cstddef>
#include <cstdint>

#define NN 50000
#define DEG 8
#define EE (NN*DEG)

// ---------------------------------------------------------------------------
// K0: build neighbor lists (constant degree 8) via atomic counters
// ---------------------------------------------------------------------------
__global__ void k_build_nbr(const int* __restrict__ ef, int* __restrict__ cnt,
                            int* __restrict__ fwd_nbr, int* __restrict__ rev_nbr) {
    int e = blockIdx.x * blockDim.x + threadIdx.x;
    if (e >= EE) return;
    int s = ef[e], d = ef[EE + e];
    int p = atomicAdd(&cnt[d], 1);
    fwd_nbr[d * DEG + p] = s;
    int q = atomicAdd(&cnt[NN + s], 1);
    rev_nbr[s * DEG + q] = d;
}

// ---------------------------------------------------------------------------
// K0b: fold post_W [16][416][32] -> Pfold [16][160][32]
// (deg==8 everywhere -> degree scalers are exactly 1; the three agg copies sum)
// ---------------------------------------------------------------------------
__global__ void k_fold_post(const float* __restrict__ post_W, float* __restrict__ Pfold) {
    int idx = blockIdx.x * blockDim.x + threadIdx.x;
    const int total = 16 * 160 * 32;
    if (idx >= total) return;
    int g = idx & 31;
    int row = (idx >> 5) % 160;
    int m = idx / (160 * 32);
    const float* W = post_W + (size_t)m * 416 * 32;
    float v;
    if (row < 32) v = W[row * 32 + g];
    else {
        int r = row - 32;
        v = W[(32 + r) * 32 + g] + W[(160 + r) * 32 + g] + W[(288 + r) * 32 + g];
    }
    Pfold[idx] = v;
}

// ---------------------------------------------------------------------------
// K1: [nrows,128] @ [128,128] + bias (+relu) -> Y
// ---------------------------------------------------------------------------
template<int RELU>
__global__ __launch_bounds__(256) void k_gemm128(
    const float* __restrict__ X, const float* __restrict__ W,
    const float* __restrict__ b, float* __restrict__ Y, int nrows) {
    __shared__ float Ws[64 * 128];
    __shared__ float Xs[32 * 128];
    int tid = threadIdx.x;
    int row0 = blockIdx.x * 32;
    for (int i = tid; i < 32 * 128; i += 256) {
        int r = row0 + (i >> 7);
        Xs[i] = (r < nrows) ? X[(size_t)r * 128 + (i & 127)] : 0.f;
    }
    int col = tid & 127, rb = tid >> 7;
    float acc[16];
#pragma unroll
    for (int i = 0; i < 16; i++) acc[i] = 0.f;
    for (int kc = 0; kc < 2; kc++) {
        __syncthreads();
        for (int i = tid; i < 64 * 128; i += 256) Ws[i] = W[kc * 64 * 128 + i];
        __syncthreads();
        for (int k = 0; k < 64; k++) {
            float w = Ws[k * 128 + col];
#pragma unroll
            for (int i = 0; i < 16; i++)
                acc[i] += Xs[(rb + 2 * i) * 128 + kc * 64 + k] * w;
        }
    }
    float bias = b[col];
#pragma unroll
    for (int i = 0; i < 16; i++) {
        int r = row0 + rb + 2 * i;
        if (r < nrows) {
            float v = acc[i] + bias;
            if (RELU) v = fmaxf(v, 0.f);
            Y[(size_t)r * 128 + col] = v;
        }
    }
}

// ---------------------------------------------------------------------------
// K1b: fused lin GEMM: [nrows,256] @ [256,128] + (b0+b1), BN partial sums
// (K=256 is lin_W[l,0] stacked over lin_W[l,1], contiguous in memory)
// ---------------------------------------------------------------------------
__global__ __launch_bounds__(256) void k_gemm256_bn(
    const float* __restrict__ X, const float* __restrict__ W,
    const float* __restrict__ b0, const float* __restrict__ b1,
    float* __restrict__ Y, int nrows,
    float* __restrict__ bnsum, float* __restrict__ bnsum2) {
    __shared__ float Ws[64 * 128];  // 32 KB
    __shared__ float Xs[32 * 64];   // 8 KB
    int tid = threadIdx.x;
    int row0 = blockIdx.x * 32;
    int col = tid & 127, rb = tid >> 7;
    float acc[16];
#pragma unroll
    for (int i = 0; i < 16; i++) acc[i] = 0.f;
    for (int kc = 0; kc < 4; kc++) {
        __syncthreads();
        for (int i = tid; i < 64 * 128; i += 256) Ws[i] = W[kc * 64 * 128 + i];
        for (int i = tid; i < 32 * 64; i += 256) {
            int r = row0 + (i >> 6);
            Xs[i] = (r < nrows) ? X[(size_t)r * 256 + kc * 64 + (i & 63)] : 0.f;
        }
        __syncthreads();
        for (int k = 0; k < 64; k++) {
            float w = Ws[k * 128 + col];
#pragma unroll
            for (int i = 0; i < 16; i++)
                acc[i] += Xs[(rb + 2 * i) * 64 + k] * w;
        }
    }
    float bias = b0[col] + b1[col];
    float ls = 0.f, ls2 = 0.f;
#pragma unroll
    for (int i = 0; i < 16; i++) {
        int r = row0 + rb + 2 * i;
        if (r < nrows) {
            float v = acc[i] + bias;
            Y[(size_t)r * 128 + col] = v;
            ls += v; ls2 += v * v;
        }
    }
    __syncthreads();
    Xs[tid] = ls; Ws[tid] = ls2;
    __syncthreads();
    if (tid < 128) {
        atomicAdd(&bnsum[col], Xs[tid] + Xs[tid + 128]);
        atomicAdd(&bnsum2[col], Ws[tid] + Ws[tid + 128]);
    }
}

// ---------------------------------------------------------------------------
// K2: B planes. B_r[n,c] = h[n, t*32..] @ pre_W[l,r,t, 32+f, g]  (src half)
// ---------------------------------------------------------------------------
__global__ __launch_bounds__(256) void k_preB(
    const float* __restrict__ hbuf, const float* __restrict__ pre_W,
    int layer, float* __restrict__ Bplanes) {
    __shared__ float Wb[2 * 4 * 32 * 32];  // 32 KB
    __shared__ float Xs[16 * 128];         // 8 KB
    int tid = threadIdx.x;
    for (int i = tid; i < 8192; i += 256) {
        int g = i & 31, f = (i >> 5) & 31, t = (i >> 10) & 3, r = i >> 12;
        Wb[i] = pre_W[((((layer * 2 + r) * 4 + t) * 64) + 32 + f) * 32 + g];
    }
    int r = tid >> 7, c = tid & 127, t = c >> 5, g = c & 31;
    const float* wp = &Wb[((r * 4 + t) * 32) * 32 + g];
    for (int base = blockIdx.x * 16; base < NN; base += gridDim.x * 16) {
        __syncthreads();
        for (int i = tid; i < 16 * 128; i += 256) {
            int n = base + (i >> 7);
            Xs[i] = (n < NN) ? hbuf[(size_t)n * 128 + (i & 127)] : 0.f;
        }
        __syncthreads();
        for (int n = 0; n < 16; n++) {
            if (base + n >= NN) break;
            float acc = 0.f;
#pragma unroll
            for (int f = 0; f < 32; f++) acc += Xs[n * 128 + t * 32 + f] * wp[f * 32];
            Bplanes[(size_t)r * NN * 128 + (size_t)(base + n) * 128 + c] = acc;
        }
    }
}

// ---------------------------------------------------------------------------
// K3: aggregation + folded post-GEMM. ONE TOWER PER BLOCK (tower-separable:
// post_W block-diagonal per tower). grid.y = rel*4 + tower. Slot stats are
// private to 32 lanes of one wave -> no __syncthreads in the node loop.
//   msg_k = A[d] + B[nbr_k] + pre_b (A const across k):
//   mean/min/max shift by A+pre_b; std is shift-invariant.
// ---------------------------------------------------------------------------
__global__ __launch_bounds__(256) void k_agg(
    const float* __restrict__ hbuf, const float* __restrict__ Bplanes,
    const int* __restrict__ fwd_nbr, const int* __restrict__ rev_nbr,
    const float* __restrict__ pre_W, const float* __restrict__ pre_b,
    const float* __restrict__ post_b, const float* __restrict__ Pfold,
    int layer, float* __restrict__ poc) {
    __shared__ float Pf[160 * 32];      // 20 KB folded post (this tower)
    __shared__ float Wt[32 * 32];       // 4 KB pre_W top (dst-side, this tower)
    __shared__ float stats[8][5 * 32];  // 5 KB [xt|mean|mn|mx|std] x 8 slots
    int tid = threadIdx.x;
    int rel = blockIdx.y >> 2;
    int tw  = blockIdx.y & 3;
    int m = layer * 2 + rel;
    const int* nbr = rel ? rev_nbr : fwd_nbr;
    const float* Bplane = Bplanes + (size_t)rel * NN * 128;
    for (int i = tid; i < 160 * 32; i += 256)
        Pf[i] = Pfold[((size_t)m * 4 + tw) * 160 * 32 + i];
    for (int i = tid; i < 32 * 32; i += 256) {
        int f = i >> 5, g = i & 31;
        Wt[i] = pre_W[((m * 4 + tw) * 64 + f) * 32 + g];
    }
    __syncthreads();
    int slot = tid >> 5;             // 0..7 (nodes per iteration)
    int g = tid & 31;
    int c = tw * 32 + g;             // feature within [0,128)
    float preb = pre_b[m * 128 + c];
    float postb = post_b[m * 128 + c];
    float* S = stats[slot];
    for (int base = blockIdx.x * 8; base < NN; base += gridDim.x * 8) {
        int d = base + slot;
        bool valid = d < NN;
        S[g] = valid ? hbuf[(size_t)d * 128 + c] : 0.f;  // xt slice
        // intra-wave LDS: no barrier needed (slot spans 32 lanes of one wave)
        float A = 0.f;
#pragma unroll
        for (int f = 0; f < 32; f++) A += S[f] * Wt[f * 32 + g];
        float s = 0.f, s2 = 0.f, mn = 1e30f, mx = -1e30f;
        if (valid) {
            const int4* nb4 = (const int4*)&nbr[d * 8];
            int4 na = nb4[0], nbv = nb4[1];
            int idx[8] = {na.x, na.y, na.z, na.w, nbv.x, nbv.y, nbv.z, nbv.w};
#pragma unroll
            for (int k = 0; k < 8; k++) {
                float bv = Bplane[(size_t)idx[k] * 128 + c];
                s += bv; s2 += bv * bv; mn = fminf(mn, bv); mx = fmaxf(mx, bv);
            }
        }
        float Bm = s * 0.125f;
        float stdv = sqrtf(fmaxf(s2 * 0.125f - Bm * Bm, 0.f) + 1e-5f);
        float bse = A + preb;
        S[32 + g] = bse + Bm;
        S[64 + g] = bse + mn;
        S[96 + g] = bse + mx;
        S[128 + g] = stdv;
        float acc = postb;
#pragma unroll
        for (int f = 0; f < 160; f++) acc += S[f] * Pf[f * 32 + g];
        if (valid) poc[(size_t)d * 256 + rel * 128 + c] = acc;
    }
}

// ---------------------------------------------------------------------------
// K5: BN finalize (1 block, 128 threads)
// ---------------------------------------------------------------------------
__global__ void k_bn_final(const float* __restrict__ bnsum, const float* __restrict__ bnsum2,
                           const float* __restrict__ gamma, const float* __restrict__ beta,
                           int layer, float* __restrict__ scale, float* __restrict__ shift) {
    int c = threadIdx.x;
    float mu = bnsum[c] * (1.f / NN);
    float var = bnsum2[c] * (1.f / NN) - mu * mu;
    float sc = gamma[layer * 128 + c] * rsqrtf(var + 1e-5f);
    scale[c] = sc;
    shift[c] = beta[layer * 128 + c] - mu * sc;
}

// ---------------------------------------------------------------------------
// K6: apply BN + relu (float4)
// ---------------------------------------------------------------------------
__global__ void k_bn_apply(const float4* __restrict__ y, const float* __restrict__ scale,
                           const float* __restrict__ shift, float4* __restrict__ hout) {
    int i = blockIdx.x * blockDim.x + threadIdx.x;
    if (i >= NN * 32) return;
    int cb = (i & 31) * 4;
    float4 v = y[i];
    v.x = fmaxf(scale[cb + 0] * v.x + shift[cb + 0], 0.f);
    v.y = fmaxf(scale[cb + 1] * v.y + shift[cb + 1], 0.f);
    v.z = fmaxf(scale[cb + 2] * v.z + shift[cb + 2], 0.f);
    v.w = fmaxf(scale[cb + 3] * v.w + shift[cb + 3], 0.f);
    hout[i] = v;
}

// ---------------------------------------------------------------------------
// K7b: [nrows,128] @ [128,32] + bias -> out
// ---------------------------------------------------------------------------
__global__ __launch_bounds__(256) void k_gemm_out(
    const float* __restrict__ X, const float* __restrict__ W,
    const float* __restrict__ b, float* __restrict__ Y, int nrows) {
    __shared__ float Ws[128 * 32];
    __shared__ float Xs[32 * 128];
    int tid = threadIdx.x;
    for (int i = tid; i < 128 * 32; i += 256) Ws[i] = W[i];
    int row0 = blockIdx.x * 32;
    for (int i = tid; i < 32 * 128; i += 256) {
        int r = row0 + (i >> 7);
        Xs[i] = (r < nrows) ? X[(size_t)r * 128 + (i & 127)] : 0.f;
    }
    __syncthreads();
    int col = tid & 31, rb = tid >> 5;
    float acc[4];
    float bias = b[col];
#pragma unroll
    for (int i = 0; i < 4; i++) acc[i] = bias;
    for (int k = 0; k < 128; k++) {
        float w = Ws[k * 32 + col];
#pragma unroll
        for (int i = 0; i < 4; i++) acc[i] += Xs[(rb + 8 * i) * 128 + k] * w;
    }
#pragma unroll
    for (int i = 0; i < 4; i++) {
        int r = row0 + rb + 8 * i;
        if (r < nrows) Y[(size_t)r * 32 + col] = acc[i];
    }
}

// ---------------------------------------------------------------------------
extern "C" void kernel_launch(void* const* d_in, const int* in_sizes, int n_in,
                              void* d_out, int out_size, void* d_ws, size_t ws_size,
                              hipStream_t stream) {
    const float* x      = (const float*)d_in[0];
    const float* W_in   = (const float*)d_in[1];
    const float* b_in   = (const float*)d_in[2];
    const float* pre_W  = (const float*)d_in[3];
    const float* pre_b  = (const float*)d_in[4];
    const float* post_W = (const float*)d_in[5];
    const float* post_b = (const float*)d_in[6];
    const float* lin_W  = (const float*)d_in[7];
    const float* lin_b  = (const float*)d_in[8];
    const float* bn_g   = (const float*)d_in[9];
    const float* bn_b   = (const float*)d_in[10];
    const float* mlp_W1 = (const float*)d_in[11];
    const float* mlp_b1 = (const float*)d_in[12];
    const float* mlp_W2 = (const float*)d_in[13];
    const float* mlp_b2 = (const float*)d_in[14];
    const int*   edge   = (const int*)d_in[15];
    float* out = (float*)d_out;

    char* w = (char*)d_ws;
    const size_t plane = (size_t)NN * 128 * sizeof(float);  // 25.6 MB
    float* hbuf = (float*)w; w += plane;
    float* ybuf = (float*)w; w += plane;
    float* Bpl  = (float*)w; w += 2 * plane;   // B0 | B1
    float* poc  = (float*)w; w += 2 * plane;   // [N,256]: rel0 cols | rel1 cols
    int* fwd_nbr = (int*)w; w += (size_t)NN * DEG * sizeof(int);
    int* rev_nbr = (int*)w; w += (size_t)NN * DEG * sizeof(int);
    int* cnt     = (int*)w; w += (size_t)2 * NN * sizeof(int);
    float* Pfold = (float*)w; w += (size_t)16 * 160 * 32 * sizeof(float);
    float* bnsum  = (float*)w; w += 128 * sizeof(float);
    float* bnsum2 = (float*)w; w += 128 * sizeof(float);
    float* scale  = (float*)w; w += 128 * sizeof(float);
    float* shift  = (float*)w; w += 128 * sizeof(float);

    const int gRows = (NN + 31) / 32;  // 1563

    hipMemsetAsync(cnt, 0, (size_t)2 * NN * sizeof(int), stream);
    k_build_nbr<<<(EE + 255) / 256, 256, 0, stream>>>(edge, cnt, fwd_nbr, rev_nbr);
    k_fold_post<<<(16 * 160 * 32 + 255) / 256, 256, 0, stream>>>(post_W, Pfold);

    // h = relu(x @ W_in + b_in)
    k_gemm128<1><<<gRows, 256, 0, stream>>>(x, W_in, b_in, hbuf, NN);

    for (int l = 0; l < 2; l++) {
        k_preB<<<256, 256, 0, stream>>>(hbuf, pre_W, l, Bpl);
        dim3 gag(128, 8);  // 1024 blocks = 4/CU; y = rel*4 + tower
        k_agg<<<gag, 256, 0, stream>>>(hbuf, Bpl, fwd_nbr, rev_nbr, pre_W, pre_b,
                                       post_b, Pfold, l, poc);
        hipMemsetAsync(bnsum, 0, 2 * 128 * sizeof(float), stream);
        k_gemm256_bn<<<gRows, 256, 0, stream>>>(
            poc, lin_W + (size_t)l * 2 * 128 * 128,
            lin_b + (size_t)(l * 2 + 0) * 128, lin_b + (size_t)(l * 2 + 1) * 128,
            ybuf, NN, bnsum, bnsum2);
        k_bn_final<<<1, 128, 0, stream>>>(bnsum, bnsum2, bn_g, bn_b, l, scale, shift);
        k_bn_apply<<<(NN * 32 + 255) / 256, 256, 0, stream>>>(
            (const float4*)ybuf, scale, shift, (float4*)hbuf);
    }

    // out = relu(h @ mlp_W1 + b1) @ mlp_W2 + b2   (reuse poc as tmp)
    k_gemm128<1><<<gRows, 256, 0, stream>>>(hbuf, mlp_W1, mlp_b1, poc, NN);
    k_gemm_out<<<gRows, 256, 0, stream>>>(poc, mlp_W2, mlp_b2, out, NN);
}

// Round 3
// 855.889 us; speedup vs baseline: 1.6165x; 1.3263x over previous
//
#include <hip/hip_runtime.h>
#include <hip/hip_fp16.h>
#include <cstddef>
#include <cstdint>

#define NN 50000
#define DEG 8
#define EE (NN*DEG)
#define RT_CNT 3125   // NN/16 row-tiles
#define KSTEPS 40     // K=1280 / 32

typedef __attribute__((ext_vector_type(8))) short short8;
typedef __attribute__((ext_vector_type(4))) float f32x4;

union Pack8 { __half h[8]; uint4 u; };

// ---------------------------------------------------------------------------
// K0: build neighbor lists (constant degree 8) via atomic counters
// ---------------------------------------------------------------------------
__global__ void k_build_nbr(const int* __restrict__ ef, int* __restrict__ cnt,
                            int* __restrict__ fwd_nbr, int* __restrict__ rev_nbr) {
    int e = blockIdx.x * blockDim.x + threadIdx.x;
    if (e >= EE) return;
    int s = ef[e], d = ef[EE + e];
    int p = atomicAdd(&cnt[d], 1);
    fwd_nbr[d * DEG + p] = s;
    int q = atomicAdd(&cnt[NN + s], 1);
    rev_nbr[s * DEG + q] = d;
}

// ---------------------------------------------------------------------------
// K0b: fold post_W [16][416][32] -> Pfold [16][160][32]
// (deg==8 everywhere -> degree scalers are exactly 1; the three agg copies sum)
// ---------------------------------------------------------------------------
__global__ void k_fold_post(const float* __restrict__ post_W, float* __restrict__ Pfold) {
    int idx = blockIdx.x * blockDim.x + threadIdx.x;
    const int total = 16 * 160 * 32;
    if (idx >= total) return;
    int g = idx & 31;
    int row = (idx >> 5) % 160;
    int m = idx / (160 * 32);
    const float* W = post_W + (size_t)m * 416 * 32;
    float v;
    if (row < 32) v = W[row * 32 + g];
    else {
        int r = row - 32;
        v = W[(32 + r) * 32 + g] + W[(160 + r) * 32 + g] + W[(288 + r) * 32 + g];
    }
    Pfold[idx] = v;
}

// ---------------------------------------------------------------------------
// K0c: build combined weight Wc[l][k=1280][n=128] = Pfold o lin_W, packed in
// MFMA B-fragment layout (f16), plus combined bias bc[l][128].
// Wc[(r,tw,p*32+g)][n] = sum_j Pfold[l*2+r][tw][p*32+g][j]*lin_W[l,r][tw*32+j][n]
// Packed: Wcp[((l*8+t)*40+s)*64+lane][e], k=s*32+(lane>>4)*8+e, n=t*16+(lane&15)
// ---------------------------------------------------------------------------
__global__ void k_make_wc(const float* __restrict__ Pfold, const float* __restrict__ lin_W,
                          const float* __restrict__ lin_b, const float* __restrict__ post_b,
                          __half* __restrict__ Wcp, float* __restrict__ bc) {
    int gid = blockIdx.x * blockDim.x + threadIdx.x;
    if (gid < 2 * 8 * KSTEPS * 64) {
        int lane = gid & 63;
        int s = (gid >> 6) % KSTEPS;
        int t = ((gid >> 6) / KSTEPS) & 7;
        int l = gid >> (6 + 3 + 0) >= 0 ? (gid / (64 * KSTEPS * 8)) : 0;
        int quad = lane >> 4, nl = lane & 15;
        int n = t * 16 + nl;
        Pack8 pk;
#pragma unroll
        for (int e = 0; e < 8; e++) {
            int k = s * 32 + quad * 8 + e;
            int r = k / 640;
            int rem = k - r * 640;
            int tw = rem / 160;
            int f = rem - tw * 160;
            const float* Pf = &Pfold[((((l * 2 + r) * 4 + tw) * 160) + f) * 32];
            const float* Wl = &lin_W[(((size_t)(l * 2 + r)) * 128 + tw * 32) * 128 + n];
            float v = 0.f;
#pragma unroll
            for (int j = 0; j < 32; j++) v += Pf[j] * Wl[(size_t)j * 128];
            pk.h[e] = __float2half(v);
        }
        *(uint4*)&Wcp[(size_t)gid * 8] = pk.u;
    }
    int b2 = gid - 2 * 8 * KSTEPS * 64;
    if (b2 >= 0 && b2 < 256) {
        int l = b2 >> 7, n = b2 & 127;
        float v = lin_b[(l * 2 + 0) * 128 + n] + lin_b[(l * 2 + 1) * 128 + n];
        for (int r = 0; r < 2; r++)
            for (int q = 0; q < 128; q++)
                v += post_b[(l * 2 + r) * 128 + q] *
                     lin_W[(((size_t)(l * 2 + r)) * 128 + q) * 128 + n];
        bc[b2] = v;
    }
}

// ---------------------------------------------------------------------------
// K1: [nrows,128] @ [128,128] + bias (+relu) -> Y   (fp32 VALU)
// ---------------------------------------------------------------------------
template<int RELU>
__global__ __launch_bounds__(256) void k_gemm128(
    const float* __restrict__ X, const float* __restrict__ W,
    const float* __restrict__ b, float* __restrict__ Y, int nrows) {
    __shared__ float Ws[64 * 128];
    __shared__ float Xs[32 * 128];
    int tid = threadIdx.x;
    int row0 = blockIdx.x * 32;
    for (int i = tid; i < 32 * 128; i += 256) {
        int r = row0 + (i >> 7);
        Xs[i] = (r < nrows) ? X[(size_t)r * 128 + (i & 127)] : 0.f;
    }
    int col = tid & 127, rb = tid >> 7;
    float acc[16];
#pragma unroll
    for (int i = 0; i < 16; i++) acc[i] = 0.f;
    for (int kc = 0; kc < 2; kc++) {
        __syncthreads();
        for (int i = tid; i < 64 * 128; i += 256) Ws[i] = W[kc * 64 * 128 + i];
        __syncthreads();
        for (int k = 0; k < 64; k++) {
            float w = Ws[k * 128 + col];
#pragma unroll
            for (int i = 0; i < 16; i++)
                acc[i] += Xs[(rb + 2 * i) * 128 + kc * 64 + k] * w;
        }
    }
    float bias = b[col];
#pragma unroll
    for (int i = 0; i < 16; i++) {
        int r = row0 + rb + 2 * i;
        if (r < nrows) {
            float v = acc[i] + bias;
            if (RELU) v = fmaxf(v, 0.f);
            Y[(size_t)r * 128 + col] = v;
        }
    }
}

// ---------------------------------------------------------------------------
// K2: B planes (src-side pre-projection), f16 output
// ---------------------------------------------------------------------------
__global__ __launch_bounds__(256) void k_preB(
    const float* __restrict__ hbuf, const float* __restrict__ pre_W,
    int layer, __half* __restrict__ Bplanes) {
    __shared__ float Wb[2 * 4 * 32 * 32];  // 32 KB
    __shared__ float Xs[16 * 128];         // 8 KB
    int tid = threadIdx.x;
    for (int i = tid; i < 8192; i += 256) {
        int g = i & 31, f = (i >> 5) & 31, t = (i >> 10) & 3, r = i >> 12;
        Wb[i] = pre_W[((((layer * 2 + r) * 4 + t) * 64) + 32 + f) * 32 + g];
    }
    int r = tid >> 7, c = tid & 127, t = c >> 5, g = c & 31;
    const float* wp = &Wb[((r * 4 + t) * 32) * 32 + g];
    for (int base = blockIdx.x * 16; base < NN; base += gridDim.x * 16) {
        __syncthreads();
        for (int i = tid; i < 16 * 128; i += 256) {
            int n = base + (i >> 7);
            Xs[i] = (n < NN) ? hbuf[(size_t)n * 128 + (i & 127)] : 0.f;
        }
        __syncthreads();
        for (int n = 0; n < 16; n++) {
            if (base + n >= NN) break;
            float acc = 0.f;
#pragma unroll
            for (int f = 0; f < 32; f++) acc += Xs[n * 128 + t * 32 + f] * wp[f * 32];
            Bplanes[(size_t)r * NN * 128 + (size_t)(base + n) * 128 + c] = __float2half(acc);
        }
    }
}

// ---------------------------------------------------------------------------
// K3: gather + stats, writing MFMA-A-packed f16 stats.
// Block: 512 thr = 16 node-slots x 32 g; one (rel,tower) per blockIdx.y.
// Stats per (node, rel, tw): [xt|mean|mn|mx|std] x 32 = 160 K-rows; slice
// kstep base = (rel*4+tw)*5. Pack via LDS: 16-node row-tile -> 320 x 16B
// coalesced stores in A-frag layout (m=lane&15, k=quad*8+e).
// ---------------------------------------------------------------------------
__global__ __launch_bounds__(512) void k_agg_stats(
    const float* __restrict__ hbuf, const __half* __restrict__ Bplanes,
    const int* __restrict__ fwd_nbr, const int* __restrict__ rev_nbr,
    const float* __restrict__ pre_W, const float* __restrict__ pre_b,
    int layer, __half* __restrict__ Ap) {
    __shared__ float Wt[32 * 32];   // 4 KB
    __shared__ float S[16 * 164];   // 10.5 KB (padded rows: 164)
    int tid = threadIdx.x;
    int rel = blockIdx.y >> 2, tw = blockIdx.y & 3;
    int m = layer * 2 + rel;
    const int* nbr = rel ? rev_nbr : fwd_nbr;
    const __half* Bp = Bplanes + (size_t)rel * NN * 128;
    for (int i = tid; i < 1024; i += 512) {
        int f = i >> 5, g = i & 31;
        Wt[i] = pre_W[((m * 4 + tw) * 64 + f) * 32 + g];
    }
    __syncthreads();
    int slot = tid >> 5, g = tid & 31;
    int c = tw * 32 + g;
    float preb = pre_b[m * 128 + c];
    int ks0 = (rel * 4 + tw) * 5;
    for (int rt = blockIdx.x; rt < RT_CNT; rt += gridDim.x) {
        int d = rt * 16 + slot;
        float* Sr = &S[slot * 164];
        Sr[g] = hbuf[(size_t)d * 128 + c];
        // intra-32-lane LDS (within one wave): no barrier needed
        float A = 0.f;
#pragma unroll
        for (int f = 0; f < 32; f++) A += Sr[f] * Wt[f * 32 + g];
        const int4* nb4 = (const int4*)&nbr[d * 8];
        int4 na = nb4[0], nb = nb4[1];
        int idx[8] = {na.x, na.y, na.z, na.w, nb.x, nb.y, nb.z, nb.w};
        float s = 0.f, s2 = 0.f, mn = 1e30f, mx = -1e30f;
#pragma unroll
        for (int k = 0; k < 8; k++) {
            float bv = __half2float(Bp[(size_t)idx[k] * 128 + c]);
            s += bv; s2 += bv * bv; mn = fminf(mn, bv); mx = fmaxf(mx, bv);
        }
        float Bm = s * 0.125f;
        float stdv = sqrtf(fmaxf(s2 * 0.125f - Bm * Bm, 0.f) + 1e-5f);
        float bse = A + preb;
        Sr[32 + g] = bse + Bm;
        Sr[64 + g] = bse + mn;
        Sr[96 + g] = bse + mx;
        Sr[128 + g] = stdv;
        __syncthreads();
        if (tid < 320) {  // waves 0..4 exactly
            int kl = tid >> 6, lane = tid & 63;
            int mm = lane & 15, quad = lane >> 4;
            const float* Sp = &S[mm * 164 + kl * 32 + quad * 8];
            Pack8 pk;
#pragma unroll
            for (int e = 0; e < 8; e++) pk.h[e] = __float2half(Sp[e]);
            *(uint4*)&Ap[(((size_t)rt * KSTEPS + ks0 + kl) * 64 + lane) * 8] = pk.u;
        }
        __syncthreads();
    }
}

// ---------------------------------------------------------------------------
// K4: MFMA GEMM  stats[N,1280] @ Wc[1280,128] + bc -> ybuf, fused BN sums.
// 256 thr = 4 waves; wave = one 16-row tile x 128 cols (8 accum frags).
// A and B pre-packed: every load is a coalesced per-lane dwordx4.
// ---------------------------------------------------------------------------
__global__ __launch_bounds__(256) void k_gemm_mfma(
    const __half* __restrict__ Ap, const __half* __restrict__ Wcp,
    const float* __restrict__ bc, float* __restrict__ Y,
    float* __restrict__ bnsum, float* __restrict__ bnsum2) {
    __shared__ float bnred[256];
    int tid = threadIdx.x;
    bnred[tid] = 0.f;
    __syncthreads();
    int wave = tid >> 6, lane = tid & 63;
    int rt = blockIdx.x * 4 + wave;
    bool active = rt < RT_CNT;
    f32x4 acc[8];
#pragma unroll
    for (int t = 0; t < 8; t++) acc[t] = (f32x4){0.f, 0.f, 0.f, 0.f};
    if (active) {
        const short8* Ab = (const short8*)Ap + (size_t)rt * KSTEPS * 64 + lane;
        const short8* Bb = (const short8*)Wcp + lane;
        for (int ks = 0; ks < KSTEPS; ks++) {
            short8 a = Ab[ks * 64];
#pragma unroll
            for (int t = 0; t < 8; t++) {
                short8 b = Bb[(t * KSTEPS + ks) * 64];
                acc[t] = __builtin_amdgcn_mfma_f32_16x16x32_f16(a, b, acc[t], 0, 0, 0);
            }
        }
        int nl = lane & 15, quad = lane >> 4;
#pragma unroll
        for (int t = 0; t < 8; t++) {
            int n = t * 16 + nl;
            float bias = bc[n];
            float ls = 0.f, ls2 = 0.f;
#pragma unroll
            for (int r = 0; r < 4; r++) {
                float v = acc[t][r] + bias;
                int node = rt * 16 + quad * 4 + r;
                Y[(size_t)node * 128 + n] = v;
                ls += v; ls2 += v * v;
            }
            ls += __shfl_xor(ls, 16); ls += __shfl_xor(ls, 32);
            ls2 += __shfl_xor(ls2, 16); ls2 += __shfl_xor(ls2, 32);
            if (quad == 0) { atomicAdd(&bnred[n], ls); atomicAdd(&bnred[128 + n], ls2); }
        }
    }
    __syncthreads();
    if (tid < 128) {
        atomicAdd(&bnsum[tid], bnred[tid]);
        atomicAdd(&bnsum2[tid], bnred[128 + tid]);
    }
}

// ---------------------------------------------------------------------------
// K5: BN finalize
// ---------------------------------------------------------------------------
__global__ void k_bn_final(const float* __restrict__ bnsum, const float* __restrict__ bnsum2,
                           const float* __restrict__ gamma, const float* __restrict__ beta,
                           int layer, float* __restrict__ scale, float* __restrict__ shift) {
    int c = threadIdx.x;
    float mu = bnsum[c] * (1.f / NN);
    float var = bnsum2[c] * (1.f / NN) - mu * mu;
    float sc = gamma[layer * 128 + c] * rsqrtf(var + 1e-5f);
    scale[c] = sc;
    shift[c] = beta[layer * 128 + c] - mu * sc;
}

// ---------------------------------------------------------------------------
// K6: apply BN + relu (float4)
// ---------------------------------------------------------------------------
__global__ void k_bn_apply(const float4* __restrict__ y, const float* __restrict__ scale,
                           const float* __restrict__ shift, float4* __restrict__ hout) {
    int i = blockIdx.x * blockDim.x + threadIdx.x;
    if (i >= NN * 32) return;
    int cb = (i & 31) * 4;
    float4 v = y[i];
    v.x = fmaxf(scale[cb + 0] * v.x + shift[cb + 0], 0.f);
    v.y = fmaxf(scale[cb + 1] * v.y + shift[cb + 1], 0.f);
    v.z = fmaxf(scale[cb + 2] * v.z + shift[cb + 2], 0.f);
    v.w = fmaxf(scale[cb + 3] * v.w + shift[cb + 3], 0.f);
    hout[i] = v;
}

// ---------------------------------------------------------------------------
// K7b: [nrows,128] @ [128,32] + bias -> out
// ---------------------------------------------------------------------------
__global__ __launch_bounds__(256) void k_gemm_out(
    const float* __restrict__ X, const float* __restrict__ W,
    const float* __restrict__ b, float* __restrict__ Y, int nrows) {
    __shared__ float Ws[128 * 32];
    __shared__ float Xs[32 * 128];
    int tid = threadIdx.x;
    for (int i = tid; i < 128 * 32; i += 256) Ws[i] = W[i];
    int row0 = blockIdx.x * 32;
    for (int i = tid; i < 32 * 128; i += 256) {
        int r = row0 + (i >> 7);
        Xs[i] = (r < nrows) ? X[(size_t)r * 128 + (i & 127)] : 0.f;
    }
    __syncthreads();
    int col = tid & 31, rb = tid >> 5;
    float acc[4];
    float bias = b[col];
#pragma unroll
    for (int i = 0; i < 4; i++) acc[i] = bias;
    for (int k = 0; k < 128; k++) {
        float w = Ws[k * 32 + col];
#pragma unroll
        for (int i = 0; i < 4; i++) acc[i] += Xs[(rb + 8 * i) * 128 + k] * w;
    }
#pragma unroll
    for (int i = 0; i < 4; i++) {
        int r = row0 + rb + 8 * i;
        if (r < nrows) Y[(size_t)r * 32 + col] = acc[i];
    }
}

// ---------------------------------------------------------------------------
extern "C" void kernel_launch(void* const* d_in, const int* in_sizes, int n_in,
                              void* d_out, int out_size, void* d_ws, size_t ws_size,
                              hipStream_t stream) {
    const float* x      = (const float*)d_in[0];
    const float* W_in   = (const float*)d_in[1];
    const float* b_in   = (const float*)d_in[2];
    const float* pre_W  = (const float*)d_in[3];
    const float* pre_b  = (const float*)d_in[4];
    const float* post_W = (const float*)d_in[5];
    const float* post_b = (const float*)d_in[6];
    const float* lin_W  = (const float*)d_in[7];
    const float* lin_b  = (const float*)d_in[8];
    const float* bn_g   = (const float*)d_in[9];
    const float* bn_b   = (const float*)d_in[10];
    const float* mlp_W1 = (const float*)d_in[11];
    const float* mlp_b1 = (const float*)d_in[12];
    const float* mlp_W2 = (const float*)d_in[13];
    const float* mlp_b2 = (const float*)d_in[14];
    const int*   edge   = (const int*)d_in[15];
    float* out = (float*)d_out;

    char* w = (char*)d_ws;
    const size_t plane = (size_t)NN * 128 * sizeof(float);       // 25.6 MB
    float* hbuf = (float*)w; w += plane;
    float* ybuf = (float*)w; w += plane;
    __half* Bpl = (__half*)w; w += plane;                        // both rels, f16
    __half* Ap  = (__half*)w; w += (size_t)NN * 1280 * sizeof(__half);  // 128 MB
    int* fwd_nbr = (int*)w; w += (size_t)NN * DEG * sizeof(int);
    int* rev_nbr = (int*)w; w += (size_t)NN * DEG * sizeof(int);
    int* cnt     = (int*)w; w += (size_t)2 * NN * sizeof(int);
    float* Pfold = (float*)w; w += (size_t)16 * 160 * 32 * sizeof(float);
    __half* Wcp  = (__half*)w; w += (size_t)2 * 1280 * 128 * sizeof(__half);
    float* bc    = (float*)w; w += 2 * 128 * sizeof(float);
    float* bnsum  = (float*)w; w += 128 * sizeof(float);
    float* bnsum2 = (float*)w; w += 128 * sizeof(float);
    float* scale  = (float*)w; w += 128 * sizeof(float);
    float* shift  = (float*)w; w += 128 * sizeof(float);

    const int gRows = (NN + 31) / 32;  // 1563

    hipMemsetAsync(cnt, 0, (size_t)2 * NN * sizeof(int), stream);
    k_build_nbr<<<(EE + 255) / 256, 256, 0, stream>>>(edge, cnt, fwd_nbr, rev_nbr);
    k_fold_post<<<(16 * 160 * 32 + 255) / 256, 256, 0, stream>>>(post_W, Pfold);
    k_make_wc<<<(2 * 8 * KSTEPS * 64 + 256 + 255) / 256, 256, 0, stream>>>(
        Pfold, lin_W, lin_b, post_b, Wcp, bc);

    // h = relu(x @ W_in + b_in)
    k_gemm128<1><<<gRows, 256, 0, stream>>>(x, W_in, b_in, hbuf, NN);

    for (int l = 0; l < 2; l++) {
        k_preB<<<256, 256, 0, stream>>>(hbuf, pre_W, l, Bpl);
        dim3 gag(391, 8);  // y = rel*4 + tower
        k_agg_stats<<<gag, 512, 0, stream>>>(hbuf, Bpl, fwd_nbr, rev_nbr,
                                             pre_W, pre_b, l, Ap);
        hipMemsetAsync(bnsum, 0, 2 * 128 * sizeof(float), stream);
        k_gemm_mfma<<<(RT_CNT + 3) / 4, 256, 0, stream>>>(
            Ap, Wcp + (size_t)l * 1280 * 128, bc + l * 128, ybuf, bnsum, bnsum2);
        k_bn_final<<<1, 128, 0, stream>>>(bnsum, bnsum2, bn_g, bn_b, l, scale, shift);
        k_bn_apply<<<(NN * 32 + 255) / 256, 256, 0, stream>>>(
            (const float4*)ybuf, scale, shift, (float4*)hbuf);
    }

    // out = relu(h @ mlp_W1 + b1) @ mlp_W2 + b2   (ybuf free -> reuse as tmp)
    k_gemm128<1><<<gRows, 256, 0, stream>>>(hbuf, mlp_W1, mlp_b1, ybuf, NN);
    k_gemm_out<<<gRows, 256, 0, stream>>>(ybuf, mlp_W2, mlp_b2, out, NN);
}